// Round 2
// baseline (1385.537 us; speedup 1.0000x reference)
//
#include <hip/hip_runtime.h>
#include <stdint.h>
#include <limits.h>

// WTA-LIF: x (160,128,48,48) fp32. TIME_STEP=5, bs=32, P=294912, K=58982.
// Pipeline: K1 coarse hist (12-bit keys) -> K2 bin select -> K3 candidate
// compaction -> K4 exact threshold + tie cutoff -> K5 LIF + mask.

#define TSTEP 5
#define BS 32
#define P_TOT 294912
#define P4_TOT 73728
#define K_SEL 58982
#define VTH 1.0f
#define TAU 0.5f

#define NB1 4096                  // 2^12 coarse bins
#define SH1 20                    // key >> 20 = coarse bin
#define SPLIT 8
#define CHUNK4 (P4_TOT / SPLIT)   // 9216 float4 per block
#define CAP 8192                  // candidate capacity per sample

struct SampleSel { unsigned bin1, needed, cbin, flags; };
struct FinalInfo { unsigned T; int cutoff; };

typedef float __attribute__((ext_vector_type(4))) f32x4;

// Monotonic float->uint key: bigger float <=> bigger key (NaN-free input).
__device__ __forceinline__ unsigned f2key(float f) {
    unsigned b = __float_as_uint(f);
    return b ^ ((unsigned)((int)b >> 31) | 0x80000000u);
}

// ---------------- K1: per-sample coarse histogram ----------------
__global__ __launch_bounds__(256)
void k1_hist(const float4* __restrict__ x, unsigned* __restrict__ hist)
{
    __shared__ unsigned lh[2][NB1];    // 32 KB, 2 copies (2 waves each)
    const int s = blockIdx.x, c = blockIdx.y;
    const int tid = threadIdx.x;
    const int copy = tid >> 7;
    for (int i = tid; i < 2 * NB1; i += 256) (&lh[0][0])[i] = 0u;
    __syncthreads();
    const float4* xs = x + (size_t)s * P4_TOT + (size_t)c * CHUNK4;
    for (int i = tid; i < CHUNK4; i += 256) {
        float4 v = xs[i];
        atomicAdd(&lh[copy][f2key(v.x) >> SH1], 1u);
        atomicAdd(&lh[copy][f2key(v.y) >> SH1], 1u);
        atomicAdd(&lh[copy][f2key(v.z) >> SH1], 1u);
        atomicAdd(&lh[copy][f2key(v.w) >> SH1], 1u);
    }
    __syncthreads();
    unsigned* hs = hist + (size_t)s * NB1;
    for (int b = tid; b < NB1; b += 256) {
        unsigned t = lh[0][b] + lh[1][b];
        if (t) atomicAdd(&hs[b], t);           // only ~300 nonzero bins
    }
}

// ---------------- K2: pick coarse bin + rank within it ----------------
__global__ __launch_bounds__(256)
void k2_selbin(const unsigned* __restrict__ hist, SampleSel* __restrict__ sel)
{
    __shared__ unsigned lh[NB1];
    __shared__ unsigned csum[256];
    const int s = blockIdx.x, tid = threadIdx.x;
    const unsigned* hs = hist + (size_t)s * NB1;
    for (int i = tid; i < NB1; i += 256) lh[i] = hs[i];
    __syncthreads();
    unsigned sum = 0;
    #pragma unroll
    for (int j = 0; j < 16; ++j) sum += lh[tid * 16 + j];
    csum[tid] = sum;
    __syncthreads();
    if (tid == 0) {
        unsigned r = K_SEL; int t = 255;
        for (;; --t) { unsigned cc = csum[t]; if (cc >= r) break; r -= cc; }
        int b = t * 16 + 15;
        for (;; --b) { unsigned cc = lh[b]; if (cc >= r) break; r -= cc; }
        SampleSel o; o.bin1 = (unsigned)b; o.needed = r; o.cbin = lh[b]; o.flags = 0;
        sel[s] = o;
    }
}

// ---------------- K3: compact candidates in selected coarse bin ----------------
__global__ __launch_bounds__(256)
void k3_compact(const float4* __restrict__ x, const SampleSel* __restrict__ sel,
                unsigned* __restrict__ cnt, uint2* __restrict__ cand)
{
    const int s = blockIdx.x, c = blockIdx.y;
    const int tid = threadIdx.x;
    const int lane = tid & 63;
    const unsigned bin1 = sel[s].bin1;
    const float4* xs = x + (size_t)s * P4_TOT + (size_t)c * CHUNK4;
    const int idx_base = c * CHUNK4 * 4;
    uint2* cs = cand + (size_t)s * CAP;
    for (int i = tid; i < CHUNK4; i += 256) {       // uniform trip count: ballots safe
        float4 v = xs[i];
        unsigned kk[4] = { f2key(v.x), f2key(v.y), f2key(v.z), f2key(v.w) };
        #pragma unroll
        for (int comp = 0; comp < 4; ++comp) {
            bool pred = (kk[comp] >> SH1) == bin1;
            unsigned long long m = __ballot(pred);
            if (m) {
                int lead = __ffsll((unsigned long long)m) - 1;
                unsigned base = 0;
                if (lane == lead) base = atomicAdd(&cnt[s], (unsigned)__popcll(m));
                base = (unsigned)__shfl((int)base, lead);
                if (pred) {
                    unsigned off = (unsigned)__popcll(m & ((1ull << lane) - 1ull));
                    unsigned p = base + off;
                    if (p < CAP) { uint2 e; e.x = kk[comp]; e.y = (unsigned)(idx_base + i * 4 + comp); cs[p] = e; }
                }
            }
        }
    }
}

// ---------------- K4: exact threshold + tie cutoff per sample ----------------
__global__ __launch_bounds__(256)
void k4_final(const float4* __restrict__ x, const SampleSel* __restrict__ sel,
              const unsigned* __restrict__ cnt, const uint2* __restrict__ cand,
              FinalInfo* __restrict__ fin)
{
    __shared__ uint2 lcand[CAP];       // 64 KB
    __shared__ unsigned hist[1024];    // 4 KB
    __shared__ unsigned tiebuf[2048];  // 8 KB
    __shared__ unsigned sh_b2, sh_r, sh_b3, sh_ceq, sh_tcnt;
    __shared__ int sh_cut;

    const int s = blockIdx.x, tid = threadIdx.x;
    const SampleSel ss = sel[s];
    const unsigned n_total = cnt[s];
    const unsigned bin1 = ss.bin1;
    const unsigned needed = ss.needed;
    const float4* xs = x + (size_t)s * P4_TOT;

    if (tid == 0) { sh_tcnt = 0u; sh_cut = INT_MAX; }

    unsigned T;
    if (n_total <= CAP) {
        const uint2* cs = cand + (size_t)s * CAP;
        for (int i = tid; i < (int)n_total; i += 256) lcand[i] = cs[i];
        for (int i = tid; i < 1024; i += 256) hist[i] = 0u;
        __syncthreads();
        for (int i = tid; i < (int)n_total; i += 256)
            atomicAdd(&hist[(lcand[i].x >> 10) & 0x3FFu], 1u);
        __syncthreads();
        if (tid == 0) {
            unsigned r = needed; int b = 1023;
            for (;; --b) { unsigned cc = hist[b]; if (cc >= r) break; r -= cc; }
            sh_b2 = (unsigned)b; sh_r = r;
        }
        __syncthreads();
        const unsigned b2 = sh_b2; const unsigned need2 = sh_r;
        for (int i = tid; i < 1024; i += 256) hist[i] = 0u;
        __syncthreads();
        for (int i = tid; i < (int)n_total; i += 256) {
            unsigned k = lcand[i].x;
            if (((k >> 10) & 0x3FFu) == b2) atomicAdd(&hist[k & 0x3FFu], 1u);
        }
        __syncthreads();
        if (tid == 0) {
            unsigned r = need2; int b = 1023; unsigned cc;
            for (;; --b) { cc = hist[b]; if (cc >= r) break; r -= cc; }
            sh_b3 = (unsigned)b; sh_r = r; sh_ceq = cc;
        }
        __syncthreads();
        T = (bin1 << SH1) | (b2 << 10) | sh_b3;
        const unsigned need3 = sh_r, ceq = sh_ceq;
        if (need3 < ceq) {
            for (int i = tid; i < (int)n_total; i += 256) {
                if (lcand[i].x == T) {
                    unsigned p = atomicAdd(&sh_tcnt, 1u);
                    if (p < 2048u) tiebuf[p] = lcand[i].y;
                }
            }
            __syncthreads();
            const unsigned tc = sh_tcnt;
            if (tc <= 2048u) {
                for (int t = tid; t < (int)tc; t += 256) {
                    unsigned e = tiebuf[t]; int rank = 0;
                    for (int q = 0; q < (int)tc; ++q) rank += (tiebuf[q] < e) ? 1 : 0;
                    if (rank == (int)need3 - 1) sh_cut = (int)e;
                }
            } else if (tid == 0) {
                const float* xf = (const float*)xs;
                unsigned left = need3;
                for (int i = 0; i < P_TOT; ++i)
                    if (f2key(xf[i]) == T) { if (--left == 0u) { sh_cut = i; break; } }
            }
            __syncthreads();
        }
    } else {
        // Fallback (candidate overflow): full-sample radix passes.
        for (int i = tid; i < 1024; i += 256) hist[i] = 0u;
        __syncthreads();
        for (int i = tid; i < P4_TOT; i += 256) {
            float4 v = xs[i];
            unsigned kk[4] = { f2key(v.x), f2key(v.y), f2key(v.z), f2key(v.w) };
            #pragma unroll
            for (int c2 = 0; c2 < 4; ++c2)
                if ((kk[c2] >> SH1) == bin1) atomicAdd(&hist[(kk[c2] >> 10) & 0x3FFu], 1u);
        }
        __syncthreads();
        if (tid == 0) {
            unsigned r = needed; int b = 1023;
            for (;; --b) { unsigned cc = hist[b]; if (cc >= r) break; r -= cc; }
            sh_b2 = (unsigned)b; sh_r = r;
        }
        __syncthreads();
        const unsigned pre22 = (bin1 << 10) | sh_b2; const unsigned need2 = sh_r;
        for (int i = tid; i < 1024; i += 256) hist[i] = 0u;
        __syncthreads();
        for (int i = tid; i < P4_TOT; i += 256) {
            float4 v = xs[i];
            unsigned kk[4] = { f2key(v.x), f2key(v.y), f2key(v.z), f2key(v.w) };
            #pragma unroll
            for (int c2 = 0; c2 < 4; ++c2)
                if ((kk[c2] >> 10) == pre22) atomicAdd(&hist[kk[c2] & 0x3FFu], 1u);
        }
        __syncthreads();
        if (tid == 0) {
            unsigned r = need2; int b = 1023; unsigned cc;
            for (;; --b) { cc = hist[b]; if (cc >= r) break; r -= cc; }
            sh_b3 = (unsigned)b; sh_r = r; sh_ceq = cc;
        }
        __syncthreads();
        T = (pre22 << 10) | sh_b3;
        const unsigned need3 = sh_r, ceq = sh_ceq;
        if (need3 < ceq) {
            for (int i = tid; i < P4_TOT; i += 256) {
                float4 v = xs[i];
                unsigned kk[4] = { f2key(v.x), f2key(v.y), f2key(v.z), f2key(v.w) };
                #pragma unroll
                for (int c2 = 0; c2 < 4; ++c2)
                    if (kk[c2] == T) {
                        unsigned p = atomicAdd(&sh_tcnt, 1u);
                        if (p < 2048u) tiebuf[p] = (unsigned)(i * 4 + c2);
                    }
            }
            __syncthreads();
            const unsigned tc = sh_tcnt;
            if (tc <= 2048u) {
                for (int t = tid; t < (int)tc; t += 256) {
                    unsigned e = tiebuf[t]; int rank = 0;
                    for (int q = 0; q < (int)tc; ++q) rank += (tiebuf[q] < e) ? 1 : 0;
                    if (rank == (int)need3 - 1) sh_cut = (int)e;
                }
            } else if (tid == 0) {
                const float* xf = (const float*)xs;
                unsigned left = need3;
                for (int i = 0; i < P_TOT; ++i)
                    if (f2key(xf[i]) == T) { if (--left == 0u) { sh_cut = i; break; } }
            }
            __syncthreads();
        }
    }
    if (tid == 0) { FinalInfo f; f.T = T; f.cutoff = sh_cut; fin[s] = f; }
}

// ---------------- K5: LIF recurrence + mask ----------------
__device__ __forceinline__ float lif_step(float& u, float xv, unsigned T, int cutoff, int idx)
{
    u = (u > VTH ? 0.0f : TAU * u) + xv;     // 0.5*u exact -> bitwise == jax fp32
    const bool s = u > VTH;
    const unsigned k = f2key(xv);
    const bool m = (k > T) || ((k == T) && (idx <= cutoff));
    return (s && m) ? 1.0f : 0.0f;
}

__global__ __launch_bounds__(256)
void k5_lif(const float4* __restrict__ x, const FinalInfo* __restrict__ fin,
            float4* __restrict__ out)
{
    const int j  = blockIdx.y;
    const int p4 = blockIdx.x * 256 + threadIdx.x;
    const int idx0 = p4 * 4;
    float4 u = make_float4(0.f, 0.f, 0.f, 0.f);
    #pragma unroll
    for (int t = 0; t < TSTEP; ++t) {
        const int b = t * BS + j;
        const size_t off = (size_t)b * P4_TOT + p4;
        const float4 xv = x[off];
        const FinalInfo si = fin[b];
        f32x4 o;
        o.x = lif_step(u.x, xv.x, si.T, si.cutoff, idx0 + 0);
        o.y = lif_step(u.y, xv.y, si.T, si.cutoff, idx0 + 1);
        o.z = lif_step(u.z, xv.z, si.T, si.cutoff, idx0 + 2);
        o.w = lif_step(u.w, xv.w, si.T, si.cutoff, idx0 + 3);
        __builtin_nontemporal_store(o, (f32x4*)&out[off]);   // avoid write-allocate RFO
    }
}

// ---------------- ws-too-small fallback: monolithic select (round-1 kernel) ----------------
__global__ __launch_bounds__(1024)
void wta_select_mono(const float4* __restrict__ x, FinalInfo* __restrict__ info)
{
    __shared__ unsigned h1[16][1024];
    __shared__ unsigned h2[2048];
    __shared__ int tiebuf[2048];
    __shared__ unsigned sh_bin1, sh_bin2, sh_bin3, sh_r, sh_ceq, sh_cnt;
    __shared__ int sh_cutoff;

    const int s = blockIdx.x, tid = threadIdx.x, wid = tid >> 6;
    const float4* xs = x + (size_t)s * P4_TOT;

    for (int i = tid; i < 16 * 1024; i += 1024) (&h1[0][0])[i] = 0u;
    __syncthreads();
    for (int i = tid; i < P4_TOT; i += 1024) {
        float4 v = xs[i];
        atomicAdd(&h1[wid][f2key(v.x) >> 22], 1u);
        atomicAdd(&h1[wid][f2key(v.y) >> 22], 1u);
        atomicAdd(&h1[wid][f2key(v.z) >> 22], 1u);
        atomicAdd(&h1[wid][f2key(v.w) >> 22], 1u);
    }
    __syncthreads();
    { unsigned sum = 0;
      #pragma unroll
      for (int w = 0; w < 16; ++w) sum += h1[w][tid];
      h2[tid] = sum; }
    __syncthreads();
    if (tid == 0) {
        unsigned r = K_SEL; int b = 1023;
        for (;; --b) { unsigned c = h2[b]; if (c >= r) break; r -= c; }
        sh_bin1 = (unsigned)b; sh_r = r;
    }
    __syncthreads();
    const unsigned bin1 = sh_bin1;
    for (int i = tid; i < 2048; i += 1024) h2[i] = 0u;
    __syncthreads();
    for (int i = tid; i < P4_TOT; i += 1024) {
        float4 v = xs[i]; unsigned k;
        k = f2key(v.x); if ((k >> 22) == bin1) atomicAdd(&h2[(k >> 11) & 0x7FFu], 1u);
        k = f2key(v.y); if ((k >> 22) == bin1) atomicAdd(&h2[(k >> 11) & 0x7FFu], 1u);
        k = f2key(v.z); if ((k >> 22) == bin1) atomicAdd(&h2[(k >> 11) & 0x7FFu], 1u);
        k = f2key(v.w); if ((k >> 22) == bin1) atomicAdd(&h2[(k >> 11) & 0x7FFu], 1u);
    }
    __syncthreads();
    if (tid == 0) {
        unsigned r = sh_r; int b = 2047;
        for (;; --b) { unsigned c = h2[b]; if (c >= r) break; r -= c; }
        sh_bin2 = (unsigned)b; sh_r = r;
    }
    __syncthreads();
    const unsigned pre21 = (bin1 << 11) | sh_bin2;
    for (int i = tid; i < 2048; i += 1024) h2[i] = 0u;
    __syncthreads();
    for (int i = tid; i < P4_TOT; i += 1024) {
        float4 v = xs[i]; unsigned k;
        k = f2key(v.x); if ((k >> 11) == pre21) atomicAdd(&h2[k & 0x7FFu], 1u);
        k = f2key(v.y); if ((k >> 11) == pre21) atomicAdd(&h2[k & 0x7FFu], 1u);
        k = f2key(v.z); if ((k >> 11) == pre21) atomicAdd(&h2[k & 0x7FFu], 1u);
        k = f2key(v.w); if ((k >> 11) == pre21) atomicAdd(&h2[k & 0x7FFu], 1u);
    }
    __syncthreads();
    if (tid == 0) {
        unsigned r = sh_r; int b = 2047; unsigned c;
        for (;; --b) { c = h2[b]; if (c >= r) break; r -= c; }
        sh_bin3 = (unsigned)b; sh_r = r; sh_ceq = c; sh_cnt = 0u; sh_cutoff = INT_MAX;
    }
    __syncthreads();
    const unsigned T = (pre21 << 11) | sh_bin3;
    const unsigned needed = sh_r, ceq = sh_ceq;
    if (needed < ceq) {
        for (int i = tid; i < P4_TOT; i += 1024) {
            float4 v = xs[i]; unsigned p;
            if (f2key(v.x) == T) { p = atomicAdd(&sh_cnt, 1u); if (p < 2048u) tiebuf[p] = i*4 + 0; }
            if (f2key(v.y) == T) { p = atomicAdd(&sh_cnt, 1u); if (p < 2048u) tiebuf[p] = i*4 + 1; }
            if (f2key(v.z) == T) { p = atomicAdd(&sh_cnt, 1u); if (p < 2048u) tiebuf[p] = i*4 + 2; }
            if (f2key(v.w) == T) { p = atomicAdd(&sh_cnt, 1u); if (p < 2048u) tiebuf[p] = i*4 + 3; }
        }
        __syncthreads();
        const unsigned cnt2 = sh_cnt;
        if (cnt2 <= 2048u) {
            for (int t = tid; t < (int)cnt2; t += 1024) {
                int e = tiebuf[t]; int rank = 0;
                for (int q = 0; q < (int)cnt2; ++q) rank += (tiebuf[q] < e) ? 1 : 0;
                if (rank == (int)needed - 1) sh_cutoff = e;
            }
        } else if (tid == 0) {
            const float* xf = (const float*)xs;
            unsigned left = needed;
            for (int i = 0; i < P_TOT; ++i)
                if (f2key(xf[i]) == T) { if (--left == 0u) { sh_cutoff = i; break; } }
        }
        __syncthreads();
    }
    if (tid == 0) { info[s].T = T; info[s].cutoff = sh_cutoff; }
}

extern "C" void kernel_launch(void* const* d_in, const int* in_sizes, int n_in,
                              void* d_out, int out_size, void* d_ws, size_t ws_size,
                              hipStream_t stream)
{
    const float4* x = (const float4*)d_in[0];
    float4* out = (float4*)d_out;
    char* ws = (char*)d_ws;

    const size_t HIST_B = (size_t)160 * NB1 * 4;          // 2,621,440
    size_t off = 0;
    unsigned*  hist = (unsigned*)(ws + off); off += HIST_B;
    unsigned*  cnt  = (unsigned*)(ws + off); off += 1024;   // zero region ends here
    const size_t ZERO_B = off;
    SampleSel* sel  = (SampleSel*)(ws + off); off += 4096;
    FinalInfo* fin  = (FinalInfo*)(ws + off); off += 4096;
    uint2*     cand = (uint2*)(ws + off);     off += (size_t)160 * CAP * 8;
    const size_t NEED_B = off;                              // ~13.1 MB

    if (ws_size >= NEED_B) {
        hipMemsetAsync(d_ws, 0, ZERO_B, stream);
        k1_hist  <<<dim3(160, SPLIT), 256, 0, stream>>>(x, hist);
        k2_selbin<<<160,              256, 0, stream>>>(hist, sel);
        k3_compact<<<dim3(160, SPLIT),256, 0, stream>>>(x, sel, cnt, cand);
        k4_final <<<160,              256, 0, stream>>>(x, sel, cnt, cand, fin);
        k5_lif   <<<dim3(P4_TOT / 256, BS), 256, 0, stream>>>(x, fin, out);
    } else {
        FinalInfo* fin2 = (FinalInfo*)d_ws;                 // 160 * 8 B
        wta_select_mono<<<160, 1024, 0, stream>>>(x, fin2);
        k5_lif<<<dim3(P4_TOT / 256, BS), 256, 0, stream>>>(x, fin2, out);
    }
}

// Round 3
// 513.463 us; speedup vs baseline: 2.6984x; 2.6984x over previous
//
#include <hip/hip_runtime.h>
#include <stdint.h>
#include <limits.h>

// WTA-LIF: x (160,128,48,48) fp32. TIME_STEP=5, bs=32, P=294912, K=58982.
// K3: band compaction (fixed key band + validity counts) -> K4: exact
// threshold + tie cutoff among candidates -> gated fallback (full select)
// -> K5: LIF recurrence + mask.

#define TSTEP 5
#define BS 32
#define P_TOT 294912
#define P4_TOT 73728
#define K_SEL 58982
#define VTH 1.0f
#define TAU 0.5f

#define SPLIT 16
#define CHUNK4 (P4_TOT / SPLIT)     // 4608 float4 per block
#define CAP 10240                   // global candidate capacity per sample
#define LBUF 2048                   // per-block LDS candidate buffer
#define EBUF 2048                   // K4 selected-bin buffer
#define LO_F 0.80f
#define HI_F 0.88f
#define BSHIFT 9                    // (key-LO_KEY)>>9 -> < 2623 bins
#define NBINS 4096

struct FinalInfo { unsigned T; int cutoff; };
typedef float __attribute__((ext_vector_type(4))) f32x4;

// Monotonic float->uint key: bigger float <=> bigger key (NaN-free input).
__device__ __forceinline__ unsigned f2key(float f) {
    unsigned b = __float_as_uint(f);
    return b ^ ((unsigned)((int)b >> 31) | 0x80000000u);
}

// ---------------- K3: band compaction + hi-count ----------------
__global__ __launch_bounds__(256)
void k3_band(const float4* __restrict__ x, unsigned* __restrict__ cnt,
             unsigned* __restrict__ cnt_hi, unsigned* __restrict__ ovf,
             uint2* __restrict__ cand)
{
    __shared__ uint2 buf[LBUF];
    __shared__ unsigned nbuf, sbase;
    __shared__ unsigned wsum[4];

    const int s = blockIdx.x, c = blockIdx.y;
    const int tid = threadIdx.x;
    const int lane = tid & 63, wid = tid >> 6;
    const unsigned LO = f2key(LO_F), HI = f2key(HI_F);
    const float4* xs = x + (size_t)s * P4_TOT + (size_t)c * CHUNK4;
    const int idx_base = c * CHUNK4 * 4;

    if (tid == 0) nbuf = 0u;
    __syncthreads();

    unsigned hi_cnt = 0;
    for (int i = tid; i < CHUNK4; i += 256) {
        float4 v = xs[i];
        unsigned kk[4] = { f2key(v.x), f2key(v.y), f2key(v.z), f2key(v.w) };
        #pragma unroll
        for (int comp = 0; comp < 4; ++comp) {
            unsigned k = kk[comp];
            hi_cnt += (k >= HI) ? 1u : 0u;
            if (k >= LO && k < HI) {
                unsigned p = atomicAdd(&nbuf, 1u);
                if (p < LBUF) { uint2 e; e.x = k; e.y = (unsigned)(idx_base + i * 4 + comp); buf[p] = e; }
            }
        }
    }
    // block-reduce hi_cnt (zero contention)
    #pragma unroll
    for (int o = 32; o > 0; o >>= 1) hi_cnt += __shfl_down(hi_cnt, o);
    if (lane == 0) wsum[wid] = hi_cnt;
    __syncthreads();
    if (tid == 0) {
        unsigned tot = wsum[0] + wsum[1] + wsum[2] + wsum[3];
        if (tot) atomicAdd(&cnt_hi[s], tot);
        unsigned nb = nbuf;
        if (nb > LBUF) atomicOr(&ovf[s], 1u);
        sbase = atomicAdd(&cnt[s], nb);
    }
    __syncthreads();
    const unsigned base = sbase;
    const unsigned nb = nbuf < LBUF ? nbuf : LBUF;
    uint2* cs = cand + (size_t)s * CAP;
    for (unsigned i = tid; i < nb; i += 256) {
        unsigned p = base + i;
        if (p < CAP) cs[p] = buf[i];
    }
}

// ---------------- K4: exact threshold + tie cutoff among candidates ----------------
__global__ __launch_bounds__(256)
void k4_final(const unsigned* __restrict__ cnt, const unsigned* __restrict__ cnt_hi,
              const unsigned* __restrict__ ovf, const uint2* __restrict__ cand,
              unsigned* __restrict__ flags, FinalInfo* __restrict__ fin)
{
    __shared__ uint2 ebuf[EBUF];        // 16 KB
    __shared__ unsigned hist[NBINS];    // 16 KB
    __shared__ unsigned sh_bin, sh_r, sh_m, sh_T, sh_g, sh_eq;
    __shared__ int sh_cut;

    const int s = blockIdx.x, tid = threadIdx.x;
    const unsigned LO = f2key(LO_F);
    const unsigned n = cnt[s];
    const unsigned chi = cnt_hi[s];

    const bool valid = (ovf[s] == 0u) && (n <= CAP) &&
                       (chi < (unsigned)K_SEL) && (chi + n >= (unsigned)K_SEL);
    if (!valid) { if (tid == 0) flags[s] = 1u; return; }

    const unsigned needed = (unsigned)K_SEL - chi;   // rank (1-based, from top) within band
    const uint2* cs = cand + (size_t)s * CAP;

    for (int i = tid; i < NBINS; i += 256) hist[i] = 0u;
    if (tid == 0) { sh_m = 0u; sh_cut = INT_MAX; }
    __syncthreads();
    for (unsigned i = tid; i < n; i += 256)
        atomicAdd(&hist[(cs[i].x - LO) >> BSHIFT], 1u);
    __syncthreads();
    if (tid == 0) {
        unsigned r = needed; int b = NBINS - 1;
        for (;; --b) { unsigned cc = hist[b]; if (cc >= r) break; r -= cc; }
        sh_bin = (unsigned)b; sh_r = r;
    }
    __syncthreads();
    const unsigned selbin = sh_bin, r = sh_r;

    // collect selected-bin candidates into LDS
    for (unsigned i = tid; i < n; i += 256) {
        uint2 e = cs[i];
        if (((e.x - LO) >> BSHIFT) == selbin) {
            unsigned p = atomicAdd(&sh_m, 1u);
            if (p < EBUF) ebuf[p] = e;
        }
    }
    __syncthreads();
    const unsigned m = sh_m;
    if (m > EBUF) { if (tid == 0) flags[s] = 1u; return; }

    // r-th largest key among ebuf (with multiplicity)
    for (unsigned i = tid; i < m; i += 256) {
        unsigned g = 0, eq = 0, ki = ebuf[i].x;
        for (unsigned j = 0; j < m; ++j) {
            unsigned kj = ebuf[j].x;
            g  += (kj > ki) ? 1u : 0u;
            eq += (kj == ki) ? 1u : 0u;
        }
        if (g < r && r <= g + eq) { sh_T = ki; sh_g = g; sh_eq = eq; }  // all winners agree
    }
    __syncthreads();
    const unsigned T = sh_T, ceq = sh_eq;
    const unsigned nt = r - sh_g;                 // #ties to include, 1..ceq
    if (nt < ceq) {
        // cutoff = nt-th smallest original index among key==T
        for (unsigned i = tid; i < m; i += 256) {
            if (ebuf[i].x == T) {
                unsigned yi = ebuf[i].y, rank = 0;
                for (unsigned j = 0; j < m; ++j)
                    rank += (ebuf[j].x == T && ebuf[j].y < yi) ? 1u : 0u;
                if (rank == nt - 1u) sh_cut = (int)yi;
            }
        }
        __syncthreads();
    }
    if (tid == 0) { FinalInfo f; f.T = T; f.cutoff = sh_cut; fin[s] = f; }
}

// ---------------- gated fallback: monolithic exact select ----------------
__global__ __launch_bounds__(1024)
void wta_select_mono(const float4* __restrict__ x, FinalInfo* __restrict__ info,
                     const unsigned* __restrict__ flags)
{
    if (flags && flags[blockIdx.x] == 0u) return;

    __shared__ unsigned h1[16][1024];
    __shared__ unsigned h2[2048];
    __shared__ int tiebuf[2048];
    __shared__ unsigned sh_bin1, sh_bin2, sh_bin3, sh_r, sh_ceq, sh_cnt;
    __shared__ int sh_cutoff;

    const int s = blockIdx.x, tid = threadIdx.x, wid = tid >> 6;
    const float4* xs = x + (size_t)s * P4_TOT;

    for (int i = tid; i < 16 * 1024; i += 1024) (&h1[0][0])[i] = 0u;
    __syncthreads();
    for (int i = tid; i < P4_TOT; i += 1024) {
        float4 v = xs[i];
        atomicAdd(&h1[wid][f2key(v.x) >> 22], 1u);
        atomicAdd(&h1[wid][f2key(v.y) >> 22], 1u);
        atomicAdd(&h1[wid][f2key(v.z) >> 22], 1u);
        atomicAdd(&h1[wid][f2key(v.w) >> 22], 1u);
    }
    __syncthreads();
    { unsigned sum = 0;
      #pragma unroll
      for (int w = 0; w < 16; ++w) sum += h1[w][tid];
      h2[tid] = sum; }
    __syncthreads();
    if (tid == 0) {
        unsigned r = K_SEL; int b = 1023;
        for (;; --b) { unsigned c = h2[b]; if (c >= r) break; r -= c; }
        sh_bin1 = (unsigned)b; sh_r = r;
    }
    __syncthreads();
    const unsigned bin1 = sh_bin1;
    for (int i = tid; i < 2048; i += 1024) h2[i] = 0u;
    __syncthreads();
    for (int i = tid; i < P4_TOT; i += 1024) {
        float4 v = xs[i]; unsigned k;
        k = f2key(v.x); if ((k >> 22) == bin1) atomicAdd(&h2[(k >> 11) & 0x7FFu], 1u);
        k = f2key(v.y); if ((k >> 22) == bin1) atomicAdd(&h2[(k >> 11) & 0x7FFu], 1u);
        k = f2key(v.z); if ((k >> 22) == bin1) atomicAdd(&h2[(k >> 11) & 0x7FFu], 1u);
        k = f2key(v.w); if ((k >> 22) == bin1) atomicAdd(&h2[(k >> 11) & 0x7FFu], 1u);
    }
    __syncthreads();
    if (tid == 0) {
        unsigned r = sh_r; int b = 2047;
        for (;; --b) { unsigned c = h2[b]; if (c >= r) break; r -= c; }
        sh_bin2 = (unsigned)b; sh_r = r;
    }
    __syncthreads();
    const unsigned pre21 = (bin1 << 11) | sh_bin2;
    for (int i = tid; i < 2048; i += 1024) h2[i] = 0u;
    __syncthreads();
    for (int i = tid; i < P4_TOT; i += 1024) {
        float4 v = xs[i]; unsigned k;
        k = f2key(v.x); if ((k >> 11) == pre21) atomicAdd(&h2[k & 0x7FFu], 1u);
        k = f2key(v.y); if ((k >> 11) == pre21) atomicAdd(&h2[k & 0x7FFu], 1u);
        k = f2key(v.z); if ((k >> 11) == pre21) atomicAdd(&h2[k & 0x7FFu], 1u);
        k = f2key(v.w); if ((k >> 11) == pre21) atomicAdd(&h2[k & 0x7FFu], 1u);
    }
    __syncthreads();
    if (tid == 0) {
        unsigned r = sh_r; int b = 2047; unsigned c;
        for (;; --b) { c = h2[b]; if (c >= r) break; r -= c; }
        sh_bin3 = (unsigned)b; sh_r = r; sh_ceq = c; sh_cnt = 0u; sh_cutoff = INT_MAX;
    }
    __syncthreads();
    const unsigned T = (pre21 << 11) | sh_bin3;
    const unsigned needed = sh_r, ceq = sh_ceq;
    if (needed < ceq) {
        for (int i = tid; i < P4_TOT; i += 1024) {
            float4 v = xs[i]; unsigned p;
            if (f2key(v.x) == T) { p = atomicAdd(&sh_cnt, 1u); if (p < 2048u) tiebuf[p] = i*4 + 0; }
            if (f2key(v.y) == T) { p = atomicAdd(&sh_cnt, 1u); if (p < 2048u) tiebuf[p] = i*4 + 1; }
            if (f2key(v.z) == T) { p = atomicAdd(&sh_cnt, 1u); if (p < 2048u) tiebuf[p] = i*4 + 2; }
            if (f2key(v.w) == T) { p = atomicAdd(&sh_cnt, 1u); if (p < 2048u) tiebuf[p] = i*4 + 3; }
        }
        __syncthreads();
        const unsigned cnt2 = sh_cnt;
        if (cnt2 <= 2048u) {
            for (int t = tid; t < (int)cnt2; t += 1024) {
                int e = tiebuf[t]; int rank = 0;
                for (int q = 0; q < (int)cnt2; ++q) rank += (tiebuf[q] < e) ? 1 : 0;
                if (rank == (int)needed - 1) sh_cutoff = e;
            }
        } else if (tid == 0) {
            const float* xf = (const float*)xs;
            unsigned left = needed;
            for (int i = 0; i < P_TOT; ++i)
                if (f2key(xf[i]) == T) { if (--left == 0u) { sh_cutoff = i; break; } }
        }
        __syncthreads();
    }
    if (tid == 0) { info[s].T = T; info[s].cutoff = sh_cutoff; }
}

// ---------------- K5: LIF recurrence + mask ----------------
__device__ __forceinline__ float lif_step(float& u, float xv, unsigned T, int cutoff, int idx)
{
    u = (u > VTH ? 0.0f : TAU * u) + xv;     // 0.5*u exact -> bitwise == np fp32
    const bool s = u > VTH;
    const unsigned k = f2key(xv);
    const bool m = (k > T) || ((k == T) && (idx <= cutoff));
    return (s && m) ? 1.0f : 0.0f;
}

__global__ __launch_bounds__(256)
void k5_lif(const float4* __restrict__ x, const FinalInfo* __restrict__ fin,
            float4* __restrict__ out)
{
    const int j  = blockIdx.y;
    const int p4 = blockIdx.x * 256 + threadIdx.x;
    const int idx0 = p4 * 4;
    float4 u = make_float4(0.f, 0.f, 0.f, 0.f);
    #pragma unroll
    for (int t = 0; t < TSTEP; ++t) {
        const int b = t * BS + j;
        const size_t off = (size_t)b * P4_TOT + p4;
        const float4 xv = x[off];
        const FinalInfo si = fin[b];
        f32x4 o;
        o.x = lif_step(u.x, xv.x, si.T, si.cutoff, idx0 + 0);
        o.y = lif_step(u.y, xv.y, si.T, si.cutoff, idx0 + 1);
        o.z = lif_step(u.z, xv.z, si.T, si.cutoff, idx0 + 2);
        o.w = lif_step(u.w, xv.w, si.T, si.cutoff, idx0 + 3);
        __builtin_nontemporal_store(o, (f32x4*)&out[off]);   // avoid write-allocate RFO
    }
}

extern "C" void kernel_launch(void* const* d_in, const int* in_sizes, int n_in,
                              void* d_out, int out_size, void* d_ws, size_t ws_size,
                              hipStream_t stream)
{
    const float4* x = (const float4*)d_in[0];
    float4* out = (float4*)d_out;
    char* ws = (char*)d_ws;

    size_t off = 0;
    unsigned*  cnt    = (unsigned*)(ws + off); off += 1024;
    unsigned*  cnt_hi = (unsigned*)(ws + off); off += 1024;
    unsigned*  ovf    = (unsigned*)(ws + off); off += 1024;
    unsigned*  flags  = (unsigned*)(ws + off); off += 1024;
    const size_t ZERO_B = off;                          // 4 KB zeroed per launch
    FinalInfo* fin    = (FinalInfo*)(ws + off); off += 4096;
    uint2*     cand   = (uint2*)(ws + off);     off += (size_t)160 * CAP * 8;
    const size_t NEED_B = off;                          // ~13.1 MB

    if (ws_size >= NEED_B) {
        hipMemsetAsync(d_ws, 0, ZERO_B, stream);
        k3_band <<<dim3(160, SPLIT), 256, 0, stream>>>(x, cnt, cnt_hi, ovf, cand);
        k4_final<<<160,              256, 0, stream>>>(cnt, cnt_hi, ovf, cand, flags, fin);
        wta_select_mono<<<160, 1024, 0, stream>>>(x, fin, flags);   // gated, no-op when valid
        k5_lif  <<<dim3(P4_TOT / 256, BS), 256, 0, stream>>>(x, fin, out);
    } else {
        FinalInfo* fin2 = (FinalInfo*)d_ws;             // 160 * 8 B
        wta_select_mono<<<160, 1024, 0, stream>>>(x, fin2, (const unsigned*)nullptr);
        k5_lif<<<dim3(P4_TOT / 256, BS), 256, 0, stream>>>(x, fin2, out);
    }
}

// Round 4
// 366.187 us; speedup vs baseline: 3.7837x; 1.4022x over previous
//
#include <hip/hip_runtime.h>
#include <stdint.h>
#include <limits.h>

// WTA-LIF: x (160,128,48,48) fp32. TIME_STEP=5, bs=32, P=294912, K=58982.
// K3: band compaction (fixed key band + validity counts) -> K4: exact
// threshold + tie cutoff among candidates (parallel suffix-scan select)
// -> gated fallback (full select) -> K5: LIF recurrence + mask.

#define TSTEP 5
#define BS 32
#define P_TOT 294912
#define P4_TOT 73728
#define K_SEL 58982
#define VTH 1.0f
#define TAU 0.5f

#define SPLIT 16
#define CHUNK4 (P4_TOT / SPLIT)     // 4608 float4 per block
#define CAP 10240                   // global candidate capacity per sample
#define LBUF 2048                   // per-block LDS candidate buffer
#define EBUF 2048                   // K4 selected-bin buffer
#define LO_F 0.80f
#define HI_F 0.88f
#define BSHIFT 9                    // (key-LO_KEY)>>9 -> < 2623 bins
#define NBINS 4096

struct FinalInfo { unsigned T; int cutoff; };
typedef float __attribute__((ext_vector_type(4))) f32x4;

// Monotonic float->uint key: bigger float <=> bigger key (NaN-free input).
__device__ __forceinline__ unsigned f2key(float f) {
    unsigned b = __float_as_uint(f);
    return b ^ ((unsigned)((int)b >> 31) | 0x80000000u);
}

// ---------------- K3: band compaction + hi-count ----------------
__global__ __launch_bounds__(256)
void k3_band(const float4* __restrict__ x, unsigned* __restrict__ cnt,
             unsigned* __restrict__ cnt_hi, unsigned* __restrict__ ovf,
             uint2* __restrict__ cand)
{
    __shared__ uint2 buf[LBUF];
    __shared__ unsigned nbuf, sbase;
    __shared__ unsigned wsum[4];

    const int s = blockIdx.x, c = blockIdx.y;
    const int tid = threadIdx.x;
    const int lane = tid & 63, wid = tid >> 6;
    const unsigned LO = f2key(LO_F), HI = f2key(HI_F);
    const float4* xs = x + (size_t)s * P4_TOT + (size_t)c * CHUNK4;
    const int idx_base = c * CHUNK4 * 4;

    if (tid == 0) nbuf = 0u;
    __syncthreads();

    unsigned hi_cnt = 0;
    for (int i = tid; i < CHUNK4; i += 256) {
        float4 v = xs[i];
        unsigned kk[4] = { f2key(v.x), f2key(v.y), f2key(v.z), f2key(v.w) };
        #pragma unroll
        for (int comp = 0; comp < 4; ++comp) {
            unsigned k = kk[comp];
            hi_cnt += (k >= HI) ? 1u : 0u;
            if (k >= LO && k < HI) {
                unsigned p = atomicAdd(&nbuf, 1u);
                if (p < LBUF) { uint2 e; e.x = k; e.y = (unsigned)(idx_base + i * 4 + comp); buf[p] = e; }
            }
        }
    }
    // block-reduce hi_cnt (zero contention)
    #pragma unroll
    for (int o = 32; o > 0; o >>= 1) hi_cnt += __shfl_down(hi_cnt, o);
    if (lane == 0) wsum[wid] = hi_cnt;
    __syncthreads();
    if (tid == 0) {
        unsigned tot = wsum[0] + wsum[1] + wsum[2] + wsum[3];
        if (tot) atomicAdd(&cnt_hi[s], tot);
        unsigned nb = nbuf;
        if (nb > LBUF) atomicOr(&ovf[s], 1u);
        sbase = atomicAdd(&cnt[s], nb);
    }
    __syncthreads();
    const unsigned base = sbase;
    const unsigned nb = nbuf < LBUF ? nbuf : LBUF;
    uint2* cs = cand + (size_t)s * CAP;
    for (unsigned i = tid; i < nb; i += 256) {
        unsigned p = base + i;
        if (p < CAP) cs[p] = buf[i];
    }
}

// ---------------- K4: exact threshold + tie cutoff among candidates ----------------
__global__ __launch_bounds__(256)
void k4_final(const unsigned* __restrict__ cnt, const unsigned* __restrict__ cnt_hi,
              const unsigned* __restrict__ ovf, const uint2* __restrict__ cand,
              unsigned* __restrict__ flags, FinalInfo* __restrict__ fin)
{
    __shared__ uint2 ebuf[EBUF];        // 16 KB
    __shared__ unsigned hist[NBINS];    // 16 KB
    __shared__ unsigned ssum[256];      // 1 KB: parallel suffix-scan buffer
    __shared__ unsigned sh_bin, sh_r, sh_m, sh_T, sh_g, sh_eq;
    __shared__ int sh_cut;

    const int s = blockIdx.x, tid = threadIdx.x;
    const unsigned LO = f2key(LO_F);
    const unsigned n = cnt[s];
    const unsigned chi = cnt_hi[s];

    const bool valid = (ovf[s] == 0u) && (n <= CAP) &&
                       (chi < (unsigned)K_SEL) && (chi + n >= (unsigned)K_SEL);
    if (!valid) { if (tid == 0) flags[s] = 1u; return; }

    const unsigned needed = (unsigned)K_SEL - chi;   // rank (1-based, from top) within band
    const uint2* cs = cand + (size_t)s * CAP;

    for (int i = tid; i < NBINS; i += 256) hist[i] = 0u;
    if (tid == 0) { sh_m = 0u; sh_cut = INT_MAX; }
    __syncthreads();
    for (unsigned i = tid; i < n; i += 256)
        atomicAdd(&hist[(cs[i].x - LO) >> BSHIFT], 1u);
    __syncthreads();

    // parallel bin select: per-thread 16-bin group sum, block suffix-scan,
    // crossing thread scans only its 16 bins (serial chain ~16 instead of ~2700)
    unsigned gs = 0;
    #pragma unroll
    for (int j = 0; j < 16; ++j) gs += hist[tid * 16 + j];
    ssum[tid] = gs;
    __syncthreads();
    #pragma unroll
    for (int o = 1; o < 256; o <<= 1) {
        unsigned v = (tid + o < 256) ? ssum[tid + o] : 0u;
        __syncthreads();
        ssum[tid] += v;
        __syncthreads();
    }
    {
        const unsigned above = (tid < 255) ? ssum[tid + 1] : 0u;  // strictly-above groups
        if (above < needed && needed <= above + gs) {             // unique crossing thread
            unsigned rr = needed - above;
            int b = tid * 16 + 15;
            for (;; --b) { unsigned cc = hist[b]; if (cc >= rr) break; rr -= cc; }
            sh_bin = (unsigned)b; sh_r = rr;
        }
    }
    __syncthreads();
    const unsigned selbin = sh_bin, r = sh_r;

    // collect selected-bin candidates into LDS
    for (unsigned i = tid; i < n; i += 256) {
        uint2 e = cs[i];
        if (((e.x - LO) >> BSHIFT) == selbin) {
            unsigned p = atomicAdd(&sh_m, 1u);
            if (p < EBUF) ebuf[p] = e;
        }
    }
    __syncthreads();
    const unsigned m = sh_m;
    if (m > EBUF) { if (tid == 0) flags[s] = 1u; return; }

    // r-th largest key among ebuf (with multiplicity); m is small (~2-30)
    for (unsigned i = tid; i < m; i += 256) {
        unsigned g = 0, eq = 0, ki = ebuf[i].x;
        for (unsigned j = 0; j < m; ++j) {
            unsigned kj = ebuf[j].x;
            g  += (kj > ki) ? 1u : 0u;
            eq += (kj == ki) ? 1u : 0u;
        }
        if (g < r && r <= g + eq) { sh_T = ki; sh_g = g; sh_eq = eq; }  // all winners agree
    }
    __syncthreads();
    const unsigned T = sh_T, ceq = sh_eq;
    const unsigned nt = r - sh_g;                 // #ties to include, 1..ceq
    if (nt < ceq) {
        // cutoff = nt-th smallest original index among key==T
        for (unsigned i = tid; i < m; i += 256) {
            if (ebuf[i].x == T) {
                unsigned yi = ebuf[i].y, rank = 0;
                for (unsigned j = 0; j < m; ++j)
                    rank += (ebuf[j].x == T && ebuf[j].y < yi) ? 1u : 0u;
                if (rank == nt - 1u) sh_cut = (int)yi;
            }
        }
        __syncthreads();
    }
    if (tid == 0) { FinalInfo f; f.T = T; f.cutoff = sh_cut; fin[s] = f; }
}

// ---------------- gated fallback: monolithic exact select ----------------
__global__ __launch_bounds__(1024)
void wta_select_mono(const float4* __restrict__ x, FinalInfo* __restrict__ info,
                     const unsigned* __restrict__ flags)
{
    if (flags && flags[blockIdx.x] == 0u) return;

    __shared__ unsigned h1[16][1024];
    __shared__ unsigned h2[2048];
    __shared__ int tiebuf[2048];
    __shared__ unsigned sh_bin1, sh_bin2, sh_bin3, sh_r, sh_ceq, sh_cnt;
    __shared__ int sh_cutoff;

    const int s = blockIdx.x, tid = threadIdx.x, wid = tid >> 6;
    const float4* xs = x + (size_t)s * P4_TOT;

    for (int i = tid; i < 16 * 1024; i += 1024) (&h1[0][0])[i] = 0u;
    __syncthreads();
    for (int i = tid; i < P4_TOT; i += 1024) {
        float4 v = xs[i];
        atomicAdd(&h1[wid][f2key(v.x) >> 22], 1u);
        atomicAdd(&h1[wid][f2key(v.y) >> 22], 1u);
        atomicAdd(&h1[wid][f2key(v.z) >> 22], 1u);
        atomicAdd(&h1[wid][f2key(v.w) >> 22], 1u);
    }
    __syncthreads();
    { unsigned sum = 0;
      #pragma unroll
      for (int w = 0; w < 16; ++w) sum += h1[w][tid];
      h2[tid] = sum; }
    __syncthreads();
    if (tid == 0) {
        unsigned r = K_SEL; int b = 1023;
        for (;; --b) { unsigned c = h2[b]; if (c >= r) break; r -= c; }
        sh_bin1 = (unsigned)b; sh_r = r;
    }
    __syncthreads();
    const unsigned bin1 = sh_bin1;
    for (int i = tid; i < 2048; i += 1024) h2[i] = 0u;
    __syncthreads();
    for (int i = tid; i < P4_TOT; i += 1024) {
        float4 v = xs[i]; unsigned k;
        k = f2key(v.x); if ((k >> 22) == bin1) atomicAdd(&h2[(k >> 11) & 0x7FFu], 1u);
        k = f2key(v.y); if ((k >> 22) == bin1) atomicAdd(&h2[(k >> 11) & 0x7FFu], 1u);
        k = f2key(v.z); if ((k >> 22) == bin1) atomicAdd(&h2[(k >> 11) & 0x7FFu], 1u);
        k = f2key(v.w); if ((k >> 22) == bin1) atomicAdd(&h2[(k >> 11) & 0x7FFu], 1u);
    }
    __syncthreads();
    if (tid == 0) {
        unsigned r = sh_r; int b = 2047;
        for (;; --b) { unsigned c = h2[b]; if (c >= r) break; r -= c; }
        sh_bin2 = (unsigned)b; sh_r = r;
    }
    __syncthreads();
    const unsigned pre21 = (bin1 << 11) | sh_bin2;
    for (int i = tid; i < 2048; i += 1024) h2[i] = 0u;
    __syncthreads();
    for (int i = tid; i < P4_TOT; i += 1024) {
        float4 v = xs[i]; unsigned k;
        k = f2key(v.x); if ((k >> 11) == pre21) atomicAdd(&h2[k & 0x7FFu], 1u);
        k = f2key(v.y); if ((k >> 11) == pre21) atomicAdd(&h2[k & 0x7FFu], 1u);
        k = f2key(v.z); if ((k >> 11) == pre21) atomicAdd(&h2[k & 0x7FFu], 1u);
        k = f2key(v.w); if ((k >> 11) == pre21) atomicAdd(&h2[k & 0x7FFu], 1u);
    }
    __syncthreads();
    if (tid == 0) {
        unsigned r = sh_r; int b = 2047; unsigned c;
        for (;; --b) { c = h2[b]; if (c >= r) break; r -= c; }
        sh_bin3 = (unsigned)b; sh_r = r; sh_ceq = c; sh_cnt = 0u; sh_cutoff = INT_MAX;
    }
    __syncthreads();
    const unsigned T = (pre21 << 11) | sh_bin3;
    const unsigned needed = sh_r, ceq = sh_ceq;
    if (needed < ceq) {
        for (int i = tid; i < P4_TOT; i += 1024) {
            float4 v = xs[i]; unsigned p;
            if (f2key(v.x) == T) { p = atomicAdd(&sh_cnt, 1u); if (p < 2048u) tiebuf[p] = i*4 + 0; }
            if (f2key(v.y) == T) { p = atomicAdd(&sh_cnt, 1u); if (p < 2048u) tiebuf[p] = i*4 + 1; }
            if (f2key(v.z) == T) { p = atomicAdd(&sh_cnt, 1u); if (p < 2048u) tiebuf[p] = i*4 + 2; }
            if (f2key(v.w) == T) { p = atomicAdd(&sh_cnt, 1u); if (p < 2048u) tiebuf[p] = i*4 + 3; }
        }
        __syncthreads();
        const unsigned cnt2 = sh_cnt;
        if (cnt2 <= 2048u) {
            for (int t = tid; t < (int)cnt2; t += 1024) {
                int e = tiebuf[t]; int rank = 0;
                for (int q = 0; q < (int)cnt2; ++q) rank += (tiebuf[q] < e) ? 1 : 0;
                if (rank == (int)needed - 1) sh_cutoff = e;
            }
        } else if (tid == 0) {
            const float* xf = (const float*)xs;
            unsigned left = needed;
            for (int i = 0; i < P_TOT; ++i)
                if (f2key(xf[i]) == T) { if (--left == 0u) { sh_cutoff = i; break; } }
        }
        __syncthreads();
    }
    if (tid == 0) { info[s].T = T; info[s].cutoff = sh_cutoff; }
}

// ---------------- K5: LIF recurrence + mask ----------------
__device__ __forceinline__ float lif_step(float& u, float xv, unsigned T, int cutoff, int idx)
{
    u = (u > VTH ? 0.0f : TAU * u) + xv;     // 0.5*u exact -> bitwise == np fp32
    const bool s = u > VTH;
    const unsigned k = f2key(xv);
    const bool m = (k > T) || ((k == T) && (idx <= cutoff));
    return (s && m) ? 1.0f : 0.0f;
}

__global__ __launch_bounds__(256)
void k5_lif(const float4* __restrict__ x, const FinalInfo* __restrict__ fin,
            float4* __restrict__ out)
{
    const int j  = blockIdx.y;
    const int p4 = blockIdx.x * 256 + threadIdx.x;
    const int idx0 = p4 * 4;
    float4 u = make_float4(0.f, 0.f, 0.f, 0.f);
    #pragma unroll
    for (int t = 0; t < TSTEP; ++t) {
        const int b = t * BS + j;
        const size_t off = (size_t)b * P4_TOT + p4;
        const float4 xv = x[off];
        const FinalInfo si = fin[b];
        f32x4 o;
        o.x = lif_step(u.x, xv.x, si.T, si.cutoff, idx0 + 0);
        o.y = lif_step(u.y, xv.y, si.T, si.cutoff, idx0 + 1);
        o.z = lif_step(u.z, xv.z, si.T, si.cutoff, idx0 + 2);
        o.w = lif_step(u.w, xv.w, si.T, si.cutoff, idx0 + 3);
        __builtin_nontemporal_store(o, (f32x4*)&out[off]);   // avoid write-allocate RFO
    }
}

extern "C" void kernel_launch(void* const* d_in, const int* in_sizes, int n_in,
                              void* d_out, int out_size, void* d_ws, size_t ws_size,
                              hipStream_t stream)
{
    const float4* x = (const float4*)d_in[0];
    float4* out = (float4*)d_out;
    char* ws = (char*)d_ws;

    size_t off = 0;
    unsigned*  cnt    = (unsigned*)(ws + off); off += 1024;
    unsigned*  cnt_hi = (unsigned*)(ws + off); off += 1024;
    unsigned*  ovf    = (unsigned*)(ws + off); off += 1024;
    unsigned*  flags  = (unsigned*)(ws + off); off += 1024;
    const size_t ZERO_B = off;                          // 4 KB zeroed per launch
    FinalInfo* fin    = (FinalInfo*)(ws + off); off += 4096;
    uint2*     cand   = (uint2*)(ws + off);     off += (size_t)160 * CAP * 8;
    const size_t NEED_B = off;                          // ~13.1 MB

    if (ws_size >= NEED_B) {
        hipMemsetAsync(d_ws, 0, ZERO_B, stream);
        k3_band <<<dim3(160, SPLIT), 256, 0, stream>>>(x, cnt, cnt_hi, ovf, cand);
        k4_final<<<160,              256, 0, stream>>>(cnt, cnt_hi, ovf, cand, flags, fin);
        wta_select_mono<<<160, 1024, 0, stream>>>(x, fin, flags);   // gated, no-op when valid
        k5_lif  <<<dim3(P4_TOT / 256, BS), 256, 0, stream>>>(x, fin, out);
    } else {
        FinalInfo* fin2 = (FinalInfo*)d_ws;             // 160 * 8 B
        wta_select_mono<<<160, 1024, 0, stream>>>(x, fin2, (const unsigned*)nullptr);
        k5_lif<<<dim3(P4_TOT / 256, BS), 256, 0, stream>>>(x, fin2, out);
    }
}

// Round 7
// 363.490 us; speedup vs baseline: 3.8118x; 1.0074x over previous
//
#include <hip/hip_runtime.h>
#include <stdint.h>
#include <limits.h>

// WTA-LIF: x (160,128,48,48) fp32. TIME_STEP=5, bs=32, P=294912, K=58982.
// K3: band compaction (fixed key band + validity counts) -> K4: exact
// threshold + tie cutoff among candidates (parallel suffix-scan select)
// -> gated fallback (full select) -> K5: LIF recurrence + mask.
// dur_us includes ~230us of harness re-poison traffic (755MB ws fill + out
// fill + d_in restore) -- our 4 dispatches are each < the 113us fill time.

#define TSTEP 5
#define BS 32
#define P_TOT 294912
#define P4_TOT 73728
#define K_SEL 58982
#define VTH 1.0f
#define TAU 0.5f

#define SPLIT 32
#define CHUNK4 (P4_TOT / SPLIT)     // 2304 float4 per block
#define CAP 10240                   // global candidate capacity per sample
#define LBUF 2048                   // per-block LDS candidate buffer
#define EBUF 2048                   // K4 selected-bin buffer
#define LO_F 0.80f
#define HI_F 0.88f
#define BSHIFT 9                    // (key-LO_KEY)>>9 -> < 2623 bins
#define NBINS 4096

struct FinalInfo { unsigned T; int cutoff; };
typedef float __attribute__((ext_vector_type(4))) f32x4;

// Monotonic float->uint key: bigger float <=> bigger key (NaN-free input).
__device__ __forceinline__ unsigned f2key(float f) {
    unsigned b = __float_as_uint(f);
    return b ^ ((unsigned)((int)b >> 31) | 0x80000000u);
}

// ---------------- K3: band compaction + hi-count ----------------
__global__ __launch_bounds__(256)
void k3_band(const float4* __restrict__ x, unsigned* __restrict__ cnt,
             unsigned* __restrict__ cnt_hi, unsigned* __restrict__ ovf,
             uint2* __restrict__ cand)
{
    __shared__ uint2 buf[LBUF];
    __shared__ unsigned nbuf, sbase;
    __shared__ unsigned wsum[4];

    const int s = blockIdx.x, c = blockIdx.y;
    const int tid = threadIdx.x;
    const int lane = tid & 63, wid = tid >> 6;
    const unsigned LO = f2key(LO_F), HI = f2key(HI_F);
    const float4* xs = x + (size_t)s * P4_TOT + (size_t)c * CHUNK4;
    const int idx_base = c * CHUNK4 * 4;

    if (tid == 0) nbuf = 0u;
    __syncthreads();

    unsigned hi_cnt = 0;
    for (int i = tid; i < CHUNK4; i += 256) {
        float4 v = xs[i];
        unsigned kk[4] = { f2key(v.x), f2key(v.y), f2key(v.z), f2key(v.w) };
        #pragma unroll
        for (int comp = 0; comp < 4; ++comp) {
            unsigned k = kk[comp];
            hi_cnt += (k >= HI) ? 1u : 0u;
            if (k >= LO && k < HI) {
                unsigned p = atomicAdd(&nbuf, 1u);
                if (p < LBUF) { uint2 e; e.x = k; e.y = (unsigned)(idx_base + i * 4 + comp); buf[p] = e; }
            }
        }
    }
    // block-reduce hi_cnt (zero contention)
    #pragma unroll
    for (int o = 32; o > 0; o >>= 1) hi_cnt += __shfl_down(hi_cnt, o);
    if (lane == 0) wsum[wid] = hi_cnt;
    __syncthreads();
    if (tid == 0) {
        unsigned tot = wsum[0] + wsum[1] + wsum[2] + wsum[3];
        if (tot) atomicAdd(&cnt_hi[s], tot);
        unsigned nb = nbuf;
        if (nb > LBUF) atomicOr(&ovf[s], 1u);
        sbase = atomicAdd(&cnt[s], nb);
    }
    __syncthreads();
    const unsigned base = sbase;
    const unsigned nb = nbuf < LBUF ? nbuf : LBUF;
    uint2* cs = cand + (size_t)s * CAP;
    for (unsigned i = tid; i < nb; i += 256) {
        unsigned p = base + i;
        if (p < CAP) cs[p] = buf[i];
    }
}

// ---------------- K4: exact threshold + tie cutoff among candidates ----------------
__global__ __launch_bounds__(256)
void k4_final(const unsigned* __restrict__ cnt, const unsigned* __restrict__ cnt_hi,
              const unsigned* __restrict__ ovf, const uint2* __restrict__ cand,
              unsigned* __restrict__ flags, FinalInfo* __restrict__ fin)
{
    __shared__ uint2 ebuf[EBUF];        // 16 KB
    __shared__ unsigned hist[NBINS];    // 16 KB
    __shared__ unsigned ssum[256];      // 1 KB: parallel suffix-scan buffer
    __shared__ unsigned sh_bin, sh_r, sh_m, sh_T, sh_g, sh_eq;
    __shared__ int sh_cut;

    const int s = blockIdx.x, tid = threadIdx.x;
    const unsigned LO = f2key(LO_F);
    const unsigned n = cnt[s];
    const unsigned chi = cnt_hi[s];

    const bool valid = (ovf[s] == 0u) && (n <= CAP) &&
                       (chi < (unsigned)K_SEL) && (chi + n >= (unsigned)K_SEL);
    if (!valid) { if (tid == 0) flags[s] = 1u; return; }

    const unsigned needed = (unsigned)K_SEL - chi;   // rank (1-based, from top) within band
    const uint2* cs = cand + (size_t)s * CAP;

    for (int i = tid; i < NBINS; i += 256) hist[i] = 0u;
    if (tid == 0) { sh_m = 0u; sh_cut = INT_MAX; }
    __syncthreads();
    for (unsigned i = tid; i < n; i += 256)
        atomicAdd(&hist[(cs[i].x - LO) >> BSHIFT], 1u);
    __syncthreads();

    // parallel bin select: per-thread 16-bin group sum, block suffix-scan,
    // crossing thread scans only its 16 bins (serial chain ~16 instead of ~2700)
    unsigned gs = 0;
    #pragma unroll
    for (int j = 0; j < 16; ++j) gs += hist[tid * 16 + j];
    ssum[tid] = gs;
    __syncthreads();
    #pragma unroll
    for (int o = 1; o < 256; o <<= 1) {
        unsigned v = (tid + o < 256) ? ssum[tid + o] : 0u;
        __syncthreads();
        ssum[tid] += v;
        __syncthreads();
    }
    {
        const unsigned above = (tid < 255) ? ssum[tid + 1] : 0u;  // strictly-above groups
        if (above < needed && needed <= above + gs) {             // unique crossing thread
            unsigned rr = needed - above;
            int b = tid * 16 + 15;
            for (;; --b) { unsigned cc = hist[b]; if (cc >= rr) break; rr -= cc; }
            sh_bin = (unsigned)b; sh_r = rr;
        }
    }
    __syncthreads();
    const unsigned selbin = sh_bin, r = sh_r;

    // collect selected-bin candidates into LDS
    for (unsigned i = tid; i < n; i += 256) {
        uint2 e = cs[i];
        if (((e.x - LO) >> BSHIFT) == selbin) {
            unsigned p = atomicAdd(&sh_m, 1u);
            if (p < EBUF) ebuf[p] = e;
        }
    }
    __syncthreads();
    const unsigned m = sh_m;
    if (m > EBUF) { if (tid == 0) flags[s] = 1u; return; }

    // r-th largest key among ebuf (with multiplicity); m is small (~2-30)
    for (unsigned i = tid; i < m; i += 256) {
        unsigned g = 0, eq = 0, ki = ebuf[i].x;
        for (unsigned j = 0; j < m; ++j) {
            unsigned kj = ebuf[j].x;
            g  += (kj > ki) ? 1u : 0u;
            eq += (kj == ki) ? 1u : 0u;
        }
        if (g < r && r <= g + eq) { sh_T = ki; sh_g = g; sh_eq = eq; }  // all winners agree
    }
    __syncthreads();
    const unsigned T = sh_T, ceq = sh_eq;
    const unsigned nt = r - sh_g;                 // #ties to include, 1..ceq
    if (nt < ceq) {
        // cutoff = nt-th smallest original index among key==T
        for (unsigned i = tid; i < m; i += 256) {
            if (ebuf[i].x == T) {
                unsigned yi = ebuf[i].y, rank = 0;
                for (unsigned j = 0; j < m; ++j)
                    rank += (ebuf[j].x == T && ebuf[j].y < yi) ? 1u : 0u;
                if (rank == nt - 1u) sh_cut = (int)yi;
            }
        }
        __syncthreads();
    }
    if (tid == 0) { FinalInfo f; f.T = T; f.cutoff = sh_cut; fin[s] = f; }
}

// ---------------- gated fallback: monolithic exact select (verified r1) ----------------
__global__ __launch_bounds__(1024)
void wta_select_mono(const float4* __restrict__ x, FinalInfo* __restrict__ info,
                     const unsigned* __restrict__ flags)
{
    if (flags && flags[blockIdx.x] == 0u) return;

    __shared__ unsigned h1[16][1024];
    __shared__ unsigned h2[2048];
    __shared__ int tiebuf[2048];
    __shared__ unsigned sh_bin1, sh_bin2, sh_bin3, sh_r, sh_ceq, sh_cnt;
    __shared__ int sh_cutoff;

    const int s = blockIdx.x, tid = threadIdx.x, wid = tid >> 6;
    const float4* xs = x + (size_t)s * P4_TOT;

    for (int i = tid; i < 16 * 1024; i += 1024) (&h1[0][0])[i] = 0u;
    __syncthreads();
    for (int i = tid; i < P4_TOT; i += 1024) {
        float4 v = xs[i];
        atomicAdd(&h1[wid][f2key(v.x) >> 22], 1u);
        atomicAdd(&h1[wid][f2key(v.y) >> 22], 1u);
        atomicAdd(&h1[wid][f2key(v.z) >> 22], 1u);
        atomicAdd(&h1[wid][f2key(v.w) >> 22], 1u);
    }
    __syncthreads();
    { unsigned sum = 0;
      #pragma unroll
      for (int w = 0; w < 16; ++w) sum += h1[w][tid];
      h2[tid] = sum; }
    __syncthreads();
    if (tid == 0) {
        unsigned r = K_SEL; int b = 1023;
        for (;; --b) { unsigned c = h2[b]; if (c >= r) break; r -= c; }
        sh_bin1 = (unsigned)b; sh_r = r;
    }
    __syncthreads();
    const unsigned bin1 = sh_bin1;
    for (int i = tid; i < 2048; i += 1024) h2[i] = 0u;
    __syncthreads();
    for (int i = tid; i < P4_TOT; i += 1024) {
        float4 v = xs[i]; unsigned k;
        k = f2key(v.x); if ((k >> 22) == bin1) atomicAdd(&h2[(k >> 11) & 0x7FFu], 1u);
        k = f2key(v.y); if ((k >> 22) == bin1) atomicAdd(&h2[(k >> 11) & 0x7FFu], 1u);
        k = f2key(v.z); if ((k >> 22) == bin1) atomicAdd(&h2[(k >> 11) & 0x7FFu], 1u);
        k = f2key(v.w); if ((k >> 22) == bin1) atomicAdd(&h2[(k >> 11) & 0x7FFu], 1u);
    }
    __syncthreads();
    if (tid == 0) {
        unsigned r = sh_r; int b = 2047;
        for (;; --b) { unsigned c = h2[b]; if (c >= r) break; r -= c; }
        sh_bin2 = (unsigned)b; sh_r = r;
    }
    __syncthreads();
    const unsigned pre21 = (bin1 << 11) | sh_bin2;
    for (int i = tid; i < 2048; i += 1024) h2[i] = 0u;
    __syncthreads();
    for (int i = tid; i < P4_TOT; i += 1024) {
        float4 v = xs[i]; unsigned k;
        k = f2key(v.x); if ((k >> 11) == pre21) atomicAdd(&h2[k & 0x7FFu], 1u);
        k = f2key(v.y); if ((k >> 11) == pre21) atomicAdd(&h2[k & 0x7FFu], 1u);
        k = f2key(v.z); if ((k >> 11) == pre21) atomicAdd(&h2[k & 0x7FFu], 1u);
        k = f2key(v.w); if ((k >> 11) == pre21) atomicAdd(&h2[k & 0x7FFu], 1u);
    }
    __syncthreads();
    if (tid == 0) {
        unsigned r = sh_r; int b = 2047; unsigned c;
        for (;; --b) { c = h2[b]; if (c >= r) break; r -= c; }
        sh_bin3 = (unsigned)b; sh_r = r; sh_ceq = c; sh_cnt = 0u; sh_cutoff = INT_MAX;
    }
    __syncthreads();
    const unsigned T = (pre21 << 11) | sh_bin3;
    const unsigned needed = sh_r, ceq = sh_ceq;
    if (needed < ceq) {
        for (int i = tid; i < P4_TOT; i += 1024) {
            float4 v = xs[i]; unsigned p;
            if (f2key(v.x) == T) { p = atomicAdd(&sh_cnt, 1u); if (p < 2048u) tiebuf[p] = i*4 + 0; }
            if (f2key(v.y) == T) { p = atomicAdd(&sh_cnt, 1u); if (p < 2048u) tiebuf[p] = i*4 + 1; }
            if (f2key(v.z) == T) { p = atomicAdd(&sh_cnt, 1u); if (p < 2048u) tiebuf[p] = i*4 + 2; }
            if (f2key(v.w) == T) { p = atomicAdd(&sh_cnt, 1u); if (p < 2048u) tiebuf[p] = i*4 + 3; }
        }
        __syncthreads();
        const unsigned cnt2 = sh_cnt;
        if (cnt2 <= 2048u) {
            for (int t = tid; t < (int)cnt2; t += 1024) {
                int e = tiebuf[t]; int rank = 0;
                for (int q = 0; q < (int)cnt2; ++q) rank += (tiebuf[q] < e) ? 1 : 0;
                if (rank == (int)needed - 1) sh_cutoff = e;
            }
        } else if (tid == 0) {
            const float* xf = (const float*)xs;
            unsigned left = needed;
            for (int i = 0; i < P_TOT; ++i)
                if (f2key(xf[i]) == T) { if (--left == 0u) { sh_cutoff = i; break; } }
        }
        __syncthreads();
    }
    if (tid == 0) { info[s].T = T; info[s].cutoff = sh_cutoff; }
}

// ---------------- K5: LIF recurrence + mask ----------------
__device__ __forceinline__ float lif_step(float& u, float xv, unsigned T, int cutoff, int idx)
{
    u = (u > VTH ? 0.0f : TAU * u) + xv;     // 0.5*u exact -> bitwise == np fp32
    const bool s = u > VTH;
    const unsigned k = f2key(xv);
    const bool m = (k > T) || ((k == T) && (idx <= cutoff));
    return (s && m) ? 1.0f : 0.0f;
}

__global__ __launch_bounds__(256)
void k5_lif(const float4* __restrict__ x, const FinalInfo* __restrict__ fin,
            float4* __restrict__ out)
{
    __shared__ FinalInfo sfin[TSTEP];
    const int j  = blockIdx.y;
    const int p4 = blockIdx.x * 256 + threadIdx.x;
    if (threadIdx.x < TSTEP) sfin[threadIdx.x] = fin[threadIdx.x * BS + j];
    __syncthreads();
    const int idx0 = p4 * 4;
    float4 u = make_float4(0.f, 0.f, 0.f, 0.f);
    #pragma unroll
    for (int t = 0; t < TSTEP; ++t) {
        const int b = t * BS + j;
        const size_t off = (size_t)b * P4_TOT + p4;
        const float4 xv = x[off];
        const FinalInfo si = sfin[t];
        f32x4 o;
        o.x = lif_step(u.x, xv.x, si.T, si.cutoff, idx0 + 0);
        o.y = lif_step(u.y, xv.y, si.T, si.cutoff, idx0 + 1);
        o.z = lif_step(u.z, xv.z, si.T, si.cutoff, idx0 + 2);
        o.w = lif_step(u.w, xv.w, si.T, si.cutoff, idx0 + 3);
        __builtin_nontemporal_store(o, (f32x4*)&out[off]);   // avoid write-allocate RFO
    }
}

extern "C" void kernel_launch(void* const* d_in, const int* in_sizes, int n_in,
                              void* d_out, int out_size, void* d_ws, size_t ws_size,
                              hipStream_t stream)
{
    const float4* x = (const float4*)d_in[0];
    float4* out = (float4*)d_out;
    char* ws = (char*)d_ws;

    size_t off = 0;
    unsigned*  cnt    = (unsigned*)(ws + off); off += 1024;
    unsigned*  cnt_hi = (unsigned*)(ws + off); off += 1024;
    unsigned*  ovf    = (unsigned*)(ws + off); off += 1024;
    unsigned*  flags  = (unsigned*)(ws + off); off += 1024;
    const size_t ZERO_B = off;                          // 4 KB zeroed per launch
    FinalInfo* fin    = (FinalInfo*)(ws + off); off += 4096;
    uint2*     cand   = (uint2*)(ws + off);     off += (size_t)160 * CAP * 8;
    const size_t NEED_B = off;                          // ~13.1 MB

    if (ws_size >= NEED_B) {
        hipMemsetAsync(d_ws, 0, ZERO_B, stream);
        k3_band <<<dim3(160, SPLIT), 256, 0, stream>>>(x, cnt, cnt_hi, ovf, cand);
        k4_final<<<160,              256, 0, stream>>>(cnt, cnt_hi, ovf, cand, flags, fin);
        wta_select_mono<<<160, 1024, 0, stream>>>(x, fin, flags);   // gated, no-op when valid
        k5_lif  <<<dim3(P4_TOT / 256, BS), 256, 0, stream>>>(x, fin, out);
    } else {
        FinalInfo* fin2 = (FinalInfo*)d_ws;             // 160 * 8 B
        wta_select_mono<<<160, 1024, 0, stream>>>(x, fin2, (const unsigned*)nullptr);
        k5_lif<<<dim3(P4_TOT / 256, BS), 256, 0, stream>>>(x, fin2, out);
    }
}